// Round 1
// baseline (77.631 us; speedup 1.0000x reference)
//
#include <hip/hip_runtime.h>
#include <hip/hip_bf16.h>

typedef __attribute__((ext_vector_type(8))) short bf16x8;   // 8 bf16 = 4 VGPRs
typedef __attribute__((ext_vector_type(4))) float f32x4;

#define EMB_DIM 64

// One wave (64 lanes) per token: gather weight row, project onto Poincare ball,
// round to bf16, and compute x2 = sum(bf16(e)^2) in fp32 so that the pairwise
// sqdist cancels to ~ulp for identical tokens (both paths hit the acosh clamp).
__global__ __launch_bounds__(256) void gather_project_kernel(
    const int* __restrict__ ids, const float* __restrict__ weight,
    __hip_bfloat16* __restrict__ emb, float* __restrict__ x2,
    int n_tokens_total, int vocab)
{
    int token = blockIdx.x * 4 + (threadIdx.x >> 6);
    int lane  = threadIdx.x & 63;            // lane == dim index (EMB_DIM == 64)
    if (token >= n_tokens_total) return;

    int id = ids[token];
    id = min(max(id, 0), vocab - 1);

    float w = weight[(size_t)id * EMB_DIM + lane];

    float s = w * w;
    #pragma unroll
    for (int off = 32; off >= 1; off >>= 1) s += __shfl_xor(s, off);
    float nrm = sqrtf(s);
    const float max_norm = 0.99999f;         // (1 - PROJ_EPS) / sqrt(C), C = 1
    if (nrm > max_norm) w *= max_norm / fmaxf(nrm, 1e-12f);

    __hip_bfloat16 h = __float2bfloat16(w);
    float hf = __bfloat162float(h);
    emb[(size_t)token * EMB_DIM + lane] = h;

    float s2 = hf * hf;
    #pragma unroll
    for (int off = 32; off >= 1; off >>= 1) s2 += __shfl_xor(s2, off);
    if (lane == 0) x2[token] = s2;
}

// Block = 4 waves; each wave computes one 16x16 output tile via two
// mfma_f32_16x16x32_bf16 (K = 64). Block tile = 32x32.
// A-frag: A[m = lane&15][k = (lane>>4)*8 + t]; B-frag: B[k][n = lane&15] with
// the same lane pattern (standard QK^T loading). C/D: col = lane&15,
// row = (lane>>4)*4 + reg (m89-verified).
__global__ __launch_bounds__(256) void pair_bias_kernel(
    const __hip_bfloat16* __restrict__ emb, const float* __restrict__ x2,
    const float* __restrict__ scale_p, float* __restrict__ out, int S)
{
    const int b  = blockIdx.z;
    const int i0 = blockIdx.y * 32 + ((threadIdx.x >> 7) << 4);
    const int j0 = blockIdx.x * 32 + (((threadIdx.x >> 6) & 1) << 4);
    const int lane = threadIdx.x & 63;
    const int r = lane & 15;
    const int q = lane >> 4;

    const short* E  = (const short*)emb + (size_t)b * S * EMB_DIM;
    const short* Ea = E + (i0 + r) * EMB_DIM + q * 8;
    const short* Eb = E + (j0 + r) * EMB_DIM + q * 8;

    bf16x8 a0 = *(const bf16x8*)(Ea);
    bf16x8 a1 = *(const bf16x8*)(Ea + 32);
    bf16x8 b0 = *(const bf16x8*)(Eb);
    bf16x8 b1 = *(const bf16x8*)(Eb + 32);

    f32x4 acc = {0.f, 0.f, 0.f, 0.f};
    acc = __builtin_amdgcn_mfma_f32_16x16x32_bf16(a0, b0, acc, 0, 0, 0);
    acc = __builtin_amdgcn_mfma_f32_16x16x32_bf16(a1, b1, acc, 0, 0, 0);

    const float* x2B = x2 + (size_t)b * S;
    float xj   = x2B[j0 + r];
    f32x4 xi4  = *(const f32x4*)(x2B + i0 + q * 4);
    float scale = scale_p[0];

    float* O = out + ((size_t)b * S + i0 + q * 4) * S + j0 + r;

    #pragma unroll
    for (int t = 0; t < 4; ++t) {
        float g  = acc[t];
        float xi = xi4[t];
        float sq  = fmaxf(xi + xj - 2.f * g, 0.f);          // ||xi - xj||^2
        float den = (1.f - xi) * (1.f - xj);
        // u = arg - 1, clamped to fp32(1 + 1e-7) - 1 to match the reference clamp
        float u = fmaxf(2.f * sq / den, 1.1920929e-7f);
        // acosh(1+u) = log(1 + u + sqrt(u*(u+2))) — no t^2-1 cancellation
        float dist = logf(1.f + u + sqrtf(u * (u + 2.f)));
        O[t * S] = -scale * dist;                            // scale * -dist, sqc = 1
    }
}

extern "C" void kernel_launch(void* const* d_in, const int* in_sizes, int n_in,
                              void* d_out, int out_size, void* d_ws, size_t ws_size,
                              hipStream_t stream) {
    const int*   ids     = (const int*)d_in[0];
    const float* weight  = (const float*)d_in[1];
    const float* scale_p = (const float*)d_in[2];
    float*       out     = (float*)d_out;

    const int n_tok = in_sizes[0];              // batch * seq = 4096
    const int vocab = in_sizes[1] / EMB_DIM;    // 30522
    const int S     = out_size / n_tok;         // 1024
    const int B     = n_tok / S;                // 4

    __hip_bfloat16* emb = (__hip_bfloat16*)d_ws;
    float* x2 = (float*)((char*)d_ws + (size_t)n_tok * EMB_DIM * sizeof(__hip_bfloat16));

    gather_project_kernel<<<(n_tok + 3) / 4, 256, 0, stream>>>(
        ids, weight, emb, x2, n_tok, vocab);

    dim3 grid(S / 32, S / 32, B);
    pair_bias_kernel<<<grid, 256, 0, stream>>>(emb, x2, scale_p, out, S);
}

// Round 2
// 74.297 us; speedup vs baseline: 1.0449x; 1.0449x over previous
//
#include <hip/hip_runtime.h>
#include <hip/hip_bf16.h>

typedef __attribute__((ext_vector_type(8)))  short bf16x8;   // 8 bf16 = 4 VGPRs
typedef __attribute__((ext_vector_type(4)))  float f32x4;
typedef __attribute__((ext_vector_type(16))) float f32x16;

#define EMB_DIM 64

// One wave (64 lanes) per token: gather weight row, project onto Poincare ball,
// round to bf16, and compute x2 = sum(bf16(e)^2) in fp32 so that the pairwise
// sqdist cancels to ~ulp for identical tokens (both paths hit the acosh clamp).
__global__ __launch_bounds__(256) void gather_project_kernel(
    const int* __restrict__ ids, const float* __restrict__ weight,
    __hip_bfloat16* __restrict__ emb, float* __restrict__ x2,
    int n_tokens_total, int vocab)
{
    int token = blockIdx.x * 4 + (threadIdx.x >> 6);
    int lane  = threadIdx.x & 63;            // lane == dim index (EMB_DIM == 64)
    if (token >= n_tokens_total) return;

    int id = ids[token];
    id = min(max(id, 0), vocab - 1);

    float w = weight[(size_t)id * EMB_DIM + lane];

    float s = w * w;
    #pragma unroll
    for (int off = 32; off >= 1; off >>= 1) s += __shfl_xor(s, off);
    float nrm = sqrtf(s);
    const float max_norm = 0.99999f;         // (1 - PROJ_EPS) / sqrt(C), C = 1
    if (nrm > max_norm) w *= max_norm / fmaxf(nrm, 1e-12f);

    __hip_bfloat16 h = __float2bfloat16(w);
    float hf = __bfloat162float(h);
    emb[(size_t)token * EMB_DIM + lane] = h;

    float s2 = hf * hf;
    #pragma unroll
    for (int off = 32; off >= 1; off >>= 1) s2 += __shfl_xor(s2, off);
    if (lane == 0) x2[token] = s2;
}

// Block = 4 waves arranged 2x2; each wave computes one 32x32 output tile via
// four mfma_f32_32x32x16_bf16 (K = 64). Block tile = 64x64.
// A-frag: A[m = lane&31][k = kb*16 + (lane>>5)*8 + t]; B-frag same pattern on
// rows of E (computes E . E^T). C/D: col = lane&31,
// row = (reg&3) + 8*(reg>>2) + 4*(lane>>5)  (m74/m101-verified).
__global__ __launch_bounds__(256) void pair_bias_kernel(
    const __hip_bfloat16* __restrict__ emb, const float* __restrict__ x2,
    const float* __restrict__ scale_p, float* __restrict__ out, int S)
{
    const int b    = blockIdx.z;
    const int wid  = threadIdx.x >> 6;
    const int lane = threadIdx.x & 63;
    const int i0   = blockIdx.y * 64 + (wid >> 1) * 32;
    const int j0   = blockIdx.x * 64 + (wid & 1) * 32;
    const int m    = lane & 31;
    const int h    = lane >> 5;              // 0/1: k-half selector

    const short* E  = (const short*)emb + (size_t)b * S * EMB_DIM;
    const short* Ea = E + (i0 + m) * EMB_DIM + h * 8;
    const short* Eb = E + (j0 + m) * EMB_DIM + h * 8;

    f32x16 acc = {};
    #pragma unroll
    for (int kb = 0; kb < 4; ++kb) {
        bf16x8 av = *(const bf16x8*)(Ea + kb * 16);
        bf16x8 bv = *(const bf16x8*)(Eb + kb * 16);
        acc = __builtin_amdgcn_mfma_f32_32x32x16_bf16(av, bv, acc, 0, 0, 0);
    }

    const float* x2B = x2 + (size_t)b * S;
    const float  xj    = x2B[j0 + m];
    const float  scale = scale_p[0];
    const float  omxj  = 1.f - xj;

    float* O = out + ((size_t)b * S + i0 + 4 * h) * S + j0 + m;

    #pragma unroll
    for (int g = 0; g < 4; ++g) {
        f32x4 xi4 = *(const f32x4*)(x2B + i0 + g * 8 + 4 * h);
        #pragma unroll
        for (int e = 0; e < 4; ++e) {
            float gv = acc[g * 4 + e];
            float xi = xi4[e];
            float sq  = fmaxf(xi + xj - 2.f * gv, 0.f);      // ||xi - xj||^2
            float den = (1.f - xi) * omxj;
            // u = arg - 1, clamped to fp32(1 + 1e-7) - 1 (matches ref clamp)
            float u = fmaxf(2.f * sq * __builtin_amdgcn_rcpf(den), 1.1920929e-7f);
            // acosh(1+u) = ln(1 + u + sqrt(u*(u+2))); v_log_f32 is log2
            float w = 1.f + u + __builtin_amdgcn_sqrtf(u * (u + 2.f));
            float dist = 0.69314718056f * __builtin_amdgcn_logf(w);
            O[(size_t)(g * 8 + e) * S] = -scale * dist;      // scale * -dist
        }
    }
}

extern "C" void kernel_launch(void* const* d_in, const int* in_sizes, int n_in,
                              void* d_out, int out_size, void* d_ws, size_t ws_size,
                              hipStream_t stream) {
    const int*   ids     = (const int*)d_in[0];
    const float* weight  = (const float*)d_in[1];
    const float* scale_p = (const float*)d_in[2];
    float*       out     = (float*)d_out;

    const int n_tok = in_sizes[0];              // batch * seq = 4096
    const int vocab = in_sizes[1] / EMB_DIM;    // 30522
    const int S     = out_size / n_tok;         // 1024
    const int B     = n_tok / S;                // 4

    __hip_bfloat16* emb = (__hip_bfloat16*)d_ws;
    float* x2 = (float*)((char*)d_ws + (size_t)n_tok * EMB_DIM * sizeof(__hip_bfloat16));

    gather_project_kernel<<<(n_tok + 3) / 4, 256, 0, stream>>>(
        ids, weight, emb, x2, n_tok, vocab);

    dim3 grid(S / 64, S / 64, B);
    pair_bias_kernel<<<grid, 256, 0, stream>>>(emb, x2, scale_p, out, S);
}

// Round 3
// 72.563 us; speedup vs baseline: 1.0698x; 1.0239x over previous
//
#include <hip/hip_runtime.h>
#include <hip/hip_bf16.h>

typedef __attribute__((ext_vector_type(8)))  short bf16x8;   // 8 bf16 = 4 VGPRs
typedef __attribute__((ext_vector_type(4)))  float f32x4;
typedef __attribute__((ext_vector_type(16))) float f32x16;

#define EMB_DIM 64
#define LDS_STRIDE 72   // 64 + 8 pad shorts -> 144 B row stride: b128 reads at
                        // 32-row stride start at bank 4*m%32 -> even spread

// One fused kernel. Block = 64x64 output tile, 256 threads (4 waves).
// Phase 1: gather + Poincare-project the block's 128 rows (64 i, 64 j) into
//          LDS as bf16; per-row x2 = sum(bf16(e)^2) in fp32 (deterministic
//          across blocks -> identical-token pairs cancel to ~ulp and hit the
//          acosh clamp, same as the reference).
// Phase 2: each wave: one 32x32 tile via 4x mfma_f32_32x32x16_bf16 (K=64),
//          fast-math acosh epilogue, coalesced stores.
__global__ __launch_bounds__(256) void fused_bias_kernel(
    const int* __restrict__ ids, const float* __restrict__ weight,
    const float* __restrict__ scale_p, float* __restrict__ out,
    int S, int vocab)
{
    __shared__ short Es[128 * LDS_STRIDE];   // rows 0-63: i-rows, 64-127: j-rows
    __shared__ float x2s[128];

    const int b  = blockIdx.z;
    const int i0 = blockIdx.y * 64;
    const int j0 = blockIdx.x * 64;
    const int t  = threadIdx.x;

    // ---------------- Phase 1: gather + project ----------------
    {
        const int r  = t >> 1;                       // 0..127: LDS row
        const int h2 = t & 1;                        // half-row (32 dims)
        const int grow = (r < 64) ? (i0 + r) : (j0 + r - 64);
        int id = ids[(size_t)b * S + grow];
        id = min(max(id, 0), vocab - 1);

        const f32x4* W = (const f32x4*)(weight + (size_t)id * EMB_DIM + h2 * 32);
        f32x4 v[8];
        #pragma unroll
        for (int k = 0; k < 8; ++k) v[k] = W[k];     // 8 independent 16B loads

        float s = 0.f;
        #pragma unroll
        for (int k = 0; k < 8; ++k)
            s += v[k].x * v[k].x + v[k].y * v[k].y + v[k].z * v[k].z + v[k].w * v[k].w;
        s += __shfl_xor(s, 1);                       // full-row ||x||^2

        const float max_norm = 0.99999f;             // (1 - PROJ_EPS)/sqrt(C)
        float nrm = sqrtf(s);
        float mul = (nrm > max_norm) ? (max_norm / fmaxf(nrm, 1e-12f)) : 1.f;

        const float* vf = (const float*)v;
        bf16x8 hv[4];
        float s2 = 0.f;
        #pragma unroll
        for (int k = 0; k < 32; ++k) {
            __hip_bfloat16 hb = __float2bfloat16(vf[k] * mul);
            float hf = __bfloat162float(hb);
            s2 += hf * hf;
            hv[k >> 3][k & 7] = __builtin_bit_cast(short, hb);
        }
        s2 += __shfl_xor(s2, 1);                     // x2 of the rounded row

        short* dst = Es + r * LDS_STRIDE + h2 * 32;
        #pragma unroll
        for (int k = 0; k < 4; ++k)
            *(bf16x8*)(dst + k * 8) = hv[k];
        if (h2 == 0) x2s[r] = s2;
    }
    __syncthreads();

    // ---------------- Phase 2: MFMA + epilogue ----------------
    const int wid  = t >> 6;
    const int lane = t & 63;
    const int m  = lane & 31;
    const int h  = lane >> 5;                        // k-half selector
    const int ia = (wid >> 1) * 32;                  // local i-row base
    const int jb = (wid & 1) * 32;                   // local j-row base

    const short* Ear = Es + (ia + m) * LDS_STRIDE + h * 8;
    const short* Ebr = Es + (64 + jb + m) * LDS_STRIDE + h * 8;

    f32x16 acc = {};
    #pragma unroll
    for (int kb = 0; kb < 4; ++kb) {
        bf16x8 av = *(const bf16x8*)(Ear + kb * 16);
        bf16x8 bv = *(const bf16x8*)(Ebr + kb * 16);
        acc = __builtin_amdgcn_mfma_f32_32x32x16_bf16(av, bv, acc, 0, 0, 0);
    }

    const float xj    = x2s[64 + jb + m];
    const float scale = scale_p[0];
    const float omxj  = 1.f - xj;

    float* O = out + ((size_t)b * S + i0 + ia + 4 * h) * S + j0 + jb + m;

    #pragma unroll
    for (int g = 0; g < 4; ++g) {
        f32x4 xi4 = *(const f32x4*)(x2s + ia + g * 8 + 4 * h);   // broadcast read
        #pragma unroll
        for (int e = 0; e < 4; ++e) {
            float gv = acc[g * 4 + e];
            float xi = xi4[e];
            float sq  = fmaxf(xi + xj - 2.f * gv, 0.f);          // ||xi - xj||^2
            float den = (1.f - xi) * omxj;
            // u = arg - 1, clamped to fp32(1 + 1e-7) - 1 (matches ref clamp)
            float u = fmaxf(2.f * sq * __builtin_amdgcn_rcpf(den), 1.1920929e-7f);
            // acosh(1+u) = ln(1 + u + sqrt(u*(u+2))); v_log_f32 is log2
            float w = 1.f + u + __builtin_amdgcn_sqrtf(u * (u + 2.f));
            float dist = 0.69314718056f * __builtin_amdgcn_logf(w);
            O[(size_t)(g * 8 + e) * S] = -scale * dist;          // scale * -dist
        }
    }
}

extern "C" void kernel_launch(void* const* d_in, const int* in_sizes, int n_in,
                              void* d_out, int out_size, void* d_ws, size_t ws_size,
                              hipStream_t stream) {
    const int*   ids     = (const int*)d_in[0];
    const float* weight  = (const float*)d_in[1];
    const float* scale_p = (const float*)d_in[2];
    float*       out     = (float*)d_out;

    const int n_tok = in_sizes[0];              // batch * seq = 4096
    const int vocab = in_sizes[1] / EMB_DIM;    // 30522
    const int S     = out_size / n_tok;         // 1024
    const int B     = n_tok / S;                // 4

    dim3 grid(S / 64, S / 64, B);
    fused_bias_kernel<<<grid, 256, 0, stream>>>(ids, weight, scale_p, out, S, vocab);
}